// Round 1
// baseline (168.394 us; speedup 1.0000x reference)
//
#include <hip/hip_runtime.h>

// BoundaryLoss: loss = sum_{b,c,d,h,w} sigmoid(logits) * dist(b,d,h,w) / (N4*C)
// where dist = sqrt(separable squared-EDT of (1 - one_hot(targets).sum(-1)))
// computed over the FULL [B,D,H,W] array (4 passes incl. batch axis).

#define EDT_INF 1e10f

constexpr int Bb = 2, Cc = 4, Dd = 64, Hh = 96, Ww = 96;
constexpr int DHW = Dd * Hh * Ww;        // 589824
constexpr int HW  = Hh * Ww;             // 9216
constexpr int N4  = Bb * DHW;            // 1179648
constexpr int N5  = Bb * Cc * DHW;       // 4718592
constexpr int NPART = 2048;

// f[idx] = 0 where target valid (one-hot sums to 1 -> bg==0), else INF
__global__ void init_f_kernel(const int* __restrict__ targets,
                              float* __restrict__ f) {
    int idx = blockIdx.x * blockDim.x + threadIdx.x;
    if (idx < N4) {
        int t = targets[idx];
        f[idx] = (t >= 0 && t < Cc) ? 0.0f : EDT_INF;
    }
}

// One separable EDT pass: g[i] = min_j f[j] + (i-j)^2 along axis of length N,
// element stride S, over the flattened [B,D,H,W] volume.
template<int N, int S>
__global__ void edt_pass_kernel(const float* __restrict__ f,
                                float* __restrict__ g) {
    int idx = blockIdx.x * blockDim.x + threadIdx.x;
    if (idx >= N4) return;
    int p = (idx / S) % N;          // position along the axis
    int base = idx - p * S;         // start of this line
    float best = 3.0e38f;
    #pragma unroll 8
    for (int j = 0; j < N; ++j) {
        float dj = (float)((p - j) * (p - j));
        float v = f[base + j * S] + dj;
        best = fminf(best, v);
    }
    g[idx] = best;
}

// Stage 1: partial sums of sigmoid(logits[b,c,d,h,w]) * sqrt(dist2[b,d,h,w])
__global__ void reduce_partial_kernel(const float* __restrict__ logits,
                                      const float* __restrict__ dist2,
                                      float* __restrict__ partials) {
    float acc = 0.0f;
    int stride = gridDim.x * blockDim.x;
    for (int idx = blockIdx.x * blockDim.x + threadIdx.x; idx < N5; idx += stride) {
        int b = idx / (Cc * DHW);
        int r = idx - b * (Cc * DHW);
        int q = r % DHW;                       // (d,h,w) flat index
        float x = logits[idx];
        float pr = 1.0f / (1.0f + expf(-x));   // sigmoid
        float d = sqrtf(dist2[b * DHW + q]);
        acc += pr * d;
    }
    __shared__ float sdata[256];
    sdata[threadIdx.x] = acc;
    __syncthreads();
    for (int s = 128; s > 0; s >>= 1) {
        if ((int)threadIdx.x < s) sdata[threadIdx.x] += sdata[threadIdx.x + s];
        __syncthreads();
    }
    if (threadIdx.x == 0) partials[blockIdx.x] = sdata[0];
}

// Stage 2: deterministic final reduction + scale
__global__ void reduce_final_kernel(const float* __restrict__ partials,
                                    float* __restrict__ out) {
    __shared__ float sdata[256];
    float acc = 0.0f;
    for (int i = threadIdx.x; i < NPART; i += 256) acc += partials[i];
    sdata[threadIdx.x] = acc;
    __syncthreads();
    for (int s = 128; s > 0; s >>= 1) {
        if ((int)threadIdx.x < s) sdata[threadIdx.x] += sdata[threadIdx.x + s];
        __syncthreads();
    }
    if (threadIdx.x == 0)
        out[0] = sdata[0] * (1.0f / ((float)N4 * (float)Cc));
}

extern "C" void kernel_launch(void* const* d_in, const int* in_sizes, int n_in,
                              void* d_out, int out_size, void* d_ws, size_t ws_size,
                              hipStream_t stream) {
    const float* logits  = (const float*)d_in[0];   // [B,C,D,H,W] fp32
    const int*   targets = (const int*)d_in[1];     // [B,D,H,W] int32
    float* out = (float*)d_out;                     // scalar fp32

    float* fA = (float*)d_ws;           // N4 floats
    float* fB = fA + N4;                // N4 floats
    float* partials = fB + N4;          // NPART floats

    dim3 blk(256);
    dim3 grd((N4 + 255) / 256);

    init_f_kernel<<<grd, blk, 0, stream>>>(targets, fA);
    // EDT passes in reference order: axis B (n=2), D (n=64), H (n=96), W (n=96)
    edt_pass_kernel<Bb, DHW><<<grd, blk, 0, stream>>>(fA, fB);
    edt_pass_kernel<Dd, HW ><<<grd, blk, 0, stream>>>(fB, fA);
    edt_pass_kernel<Hh, Ww ><<<grd, blk, 0, stream>>>(fA, fB);
    edt_pass_kernel<Ww, 1  ><<<grd, blk, 0, stream>>>(fB, fA);

    reduce_partial_kernel<<<NPART, blk, 0, stream>>>(logits, fA, partials);
    reduce_final_kernel<<<1, blk, 0, stream>>>(partials, out);
}

// Round 2
// 27.972 us; speedup vs baseline: 6.0202x; 6.0202x over previous
//
#include <hip/hip_runtime.h>

// BoundaryLoss: loss = sum sigmoid(logits[b,c,q]) * sqrt(edt2[b,q]) / (N4*C)
// edt2 = separable squared-EDT (4 passes: B,D,H,W) of bg = 1 - one_hot.sum().
//
// EDT pass optimization: d[i] = min_j f[j] + (i-j)^2 with f >= 0 allows an
// outward ring scan from j=i that breaks when delta^2 >= best. Every skipped
// candidate is provably >= best, so the result is BIT-EXACT equal to the
// full min (same fp32 candidate values, min is subset-invariant here).
// On real data f==0 everywhere -> each thread breaks after ring 1.

#define EDT_INF 1e10f

constexpr int Bb = 2, Cc = 4, Dd = 64, Hh = 96, Ww = 96;
constexpr int DHW = Dd * Hh * Ww;   // 589824
constexpr int HW  = Hh * Ww;        // 9216
constexpr int N4  = Bb * DHW;       // 1179648
constexpr int NPART = N4 / 256;     // 4608

// Fused: f init from targets + B-axis pass (N=2):
// d[0] = min(f0, f1+1), d[1] = min(f1, f0+1)
__global__ void initB_kernel(const int* __restrict__ targets,
                             float* __restrict__ g) {
    int q = blockIdx.x * blockDim.x + threadIdx.x;
    if (q >= DHW) return;
    int t0 = targets[q];
    int t1 = targets[DHW + q];
    float f0 = (t0 >= 0 && t0 < Cc) ? 0.0f : EDT_INF;
    float f1 = (t1 >= 0 && t1 < Cc) ? 0.0f : EDT_INF;
    g[q]       = fminf(f0, f1 + 1.0f);
    g[DHW + q] = fminf(f1, f0 + 1.0f);
}

// Ring-scan EDT pass along axis of length N, stride S.
template<int N, int S>
__global__ void edt_ring_kernel(const float* __restrict__ f,
                                float* __restrict__ g) {
    int idx = blockIdx.x * blockDim.x + threadIdx.x;
    if (idx >= N4) return;
    int p = (idx / S) % N;
    int base = idx - p * S;
    float best = f[idx];                       // ring 0
    for (int d = 1; d < N; ++d) {
        float d2 = (float)(d * d);
        if (d2 >= best) break;                 // no farther j can win
        int jm = p - d, jp = p + d;
        if (jm >= 0) best = fminf(best, f[base + jm * S] + d2);
        if (jp < N)  best = fminf(best, f[base + jp * S] + d2);
    }
    g[idx] = best;
}

// Fused final W-axis pass + sigmoid-weighted partial reduction.
__global__ void edtW_reduce_kernel(const float* __restrict__ f,
                                   const float* __restrict__ logits,
                                   float* __restrict__ partials) {
    int idx = blockIdx.x * blockDim.x + threadIdx.x;   // over [B,D,H,W]
    float acc = 0.0f;
    if (idx < N4) {
        int p = idx % Ww;
        int base = idx - p;
        float best = f[idx];
        for (int d = 1; d < Ww; ++d) {
            float d2 = (float)(d * d);
            if (d2 >= best) break;
            int jm = p - d, jp = p + d;
            if (jm >= 0) best = fminf(best, f[base + jm] + d2);
            if (jp < Ww) best = fminf(best, f[base + jp] + d2);
        }
        float dist = sqrtf(best);
        int b = idx / DHW;
        int q = idx - b * DHW;
        const float* lp = logits + (size_t)b * Cc * DHW + q;
        #pragma unroll
        for (int c = 0; c < Cc; ++c) {
            float x = lp[(size_t)c * DHW];
            acc += dist / (1.0f + expf(-x));   // sigmoid(x)*dist
        }
    }
    __shared__ float sdata[256];
    sdata[threadIdx.x] = acc;
    __syncthreads();
    for (int s = 128; s > 0; s >>= 1) {
        if ((int)threadIdx.x < s) sdata[threadIdx.x] += sdata[threadIdx.x + s];
        __syncthreads();
    }
    if (threadIdx.x == 0) partials[blockIdx.x] = sdata[0];
}

// Deterministic final reduction + scale.
__global__ void reduce_final_kernel(const float* __restrict__ partials,
                                    float* __restrict__ out) {
    __shared__ float sdata[256];
    float acc = 0.0f;
    for (int i = threadIdx.x; i < NPART; i += 256) acc += partials[i];
    sdata[threadIdx.x] = acc;
    __syncthreads();
    for (int s = 128; s > 0; s >>= 1) {
        if ((int)threadIdx.x < s) sdata[threadIdx.x] += sdata[threadIdx.x + s];
        __syncthreads();
    }
    if (threadIdx.x == 0)
        out[0] = sdata[0] * (1.0f / ((float)N4 * (float)Cc));
}

extern "C" void kernel_launch(void* const* d_in, const int* in_sizes, int n_in,
                              void* d_out, int out_size, void* d_ws, size_t ws_size,
                              hipStream_t stream) {
    const float* logits  = (const float*)d_in[0];   // [B,C,D,H,W] fp32
    const int*   targets = (const int*)d_in[1];     // [B,D,H,W] int32
    float* out = (float*)d_out;

    float* fA = (float*)d_ws;            // N4 floats
    float* fB = fA + N4;                 // N4 floats
    float* partials = fB + N4;           // NPART floats

    dim3 blk(256);

    initB_kernel<<<dim3(DHW / 256), blk, 0, stream>>>(targets, fA);
    edt_ring_kernel<Dd, HW><<<dim3(N4 / 256), blk, 0, stream>>>(fA, fB);  // D pass
    edt_ring_kernel<Hh, Ww><<<dim3(N4 / 256), blk, 0, stream>>>(fB, fA);  // H pass
    edtW_reduce_kernel<<<dim3(N4 / 256), blk, 0, stream>>>(fA, logits, partials); // W pass + reduce
    reduce_final_kernel<<<1, blk, 0, stream>>>(partials, out);
}